// Round 9
// baseline (268.936 us; speedup 1.0000x reference)
//
#include <hip/hip_runtime.h>
#include <hip/hip_bf16.h>

#define NGRAPH 4096
#define NPERS  256   // persistent blocks (1 per CU; LDS-bound anyway)

typedef __attribute__((ext_vector_type(8))) short s16x8;
typedef __attribute__((ext_vector_type(4))) float f32x4;
typedef unsigned int u32;

__device__ inline short f2bf(float f) {
  unsigned u = __float_as_uint(f);
  unsigned r = u + 0x7fffu + ((u >> 16) & 1u);
  return (short)(r >> 16);
}

// Prepack W1 (256x128 fp32, row-major) into bf16 MFMA B-fragment order.
// Fragment f = kt*8 + ct (kt,ct in 0..7). Lane l supplies B[k][c] for
// k = kt*32 + (l>>4)*8 + e (e=0..7), c = ct*16 + (l&15).
__global__ void prepack_w1(const float* __restrict__ W1, s16x8* __restrict__ w1p) {
  int t = blockIdx.x * 256 + threadIdx.x;   // 4096 threads total
  int f = t >> 6, l = t & 63;
  int kt = f >> 3, ct = f & 7;
  int k0 = kt * 32 + ((l >> 4) * 8);
  int c  = ct * 16 + (l & 15);
  s16x8 v;
  #pragma unroll
  for (int e = 0; e < 8; ++e) v[e] = f2bf(W1[(k0 + e) * 128 + c]);
  w1p[f * 64 + l] = v;
}

__device__ inline long long getb(const void* b, int i, int is64) {
  if (is64) return ((const long long*)b)[i];
  return (long long)((const int*)b)[i];
}

__device__ inline int lowb(const void* b, int n, long long v, int is64) {
  int lo = 0, hi = n;
  while (lo < hi) {
    int mid = (lo + hi) >> 1;
    if (getb(b, mid, is64) < v) lo = mid + 1; else hi = mid;
  }
  return lo;
}

__device__ inline int batch_is64(const void* batch, int N) {
  // int64 vs int32 materialization probe: an odd 32-bit word index has a zero
  // high word under int64 (values < 2^31), a near-max sorted id under int32.
  int probe = ((N & 1) == 0) ? (N - 1) : (N - 2);
  return (((const int*)batch)[probe] == 0) ? 1 : 0;
}

// One-time: offs[g] = lower_bound(batch, g).
__global__ void seg_offsets(const void* __restrict__ batch, int* __restrict__ offs, int N) {
  int g = blockIdx.x * 256 + threadIdx.x;
  const int is64 = batch_is64(batch, N);
  if (g <= NGRAPH) offs[g] = lowb(batch, N, (long long)g, is64);
}

__device__ inline float fast_tanh(float v) {
  v = fminf(fmaxf(v, -15.f), 15.f);
  float e = __expf(2.f * v);
  return __fdividef(e - 1.f, e + 1.f);
}

__device__ inline void dma16(const float* src, char* ldsdst) {
  __builtin_amdgcn_global_load_lds(
      (const __attribute__((address_space(1))) u32*)src,
      (__attribute__((address_space(3))) u32*)ldsdst,
      16, 0, 0);   // 16 B/lane: lane l -> ldsdst + l*16
}

// Persistent fused kernel. Grid = NPERS blocks (1/CU, LDS-bound). Each block
// grid-strides over 64-row tiles with DOUBLE-BUFFERED LDS staging:
//   issue DMA(tile t+NPERS) -> buf[nxt];  s_waitcnt vmcnt(16)  (counted: keeps
//   the new 16 DMAs in flight, drains tile t's + older atomics);  raw barrier.
// NO global loads inside the loop (W1 B-fragments preloaded to 128 VGPRs),
// so no compiler-inserted vmcnt wait can force the prefetch to complete.
// Phase A: MFMA scores from LDS. Phase B: pooling from LDS. Scores bounded
// (|s| <= ||W2||_1 + |b2| ~ 9) -> exp without max-subtraction; cross-tile
// segment joins via atomicAdd (accumulators zeroed every call).
__global__ __launch_bounds__(256, 1)
void gate_pool(const float* __restrict__ x, const int* __restrict__ offs,
               const float* __restrict__ b1, const float* __restrict__ W2,
               const float* __restrict__ b2p, const s16x8* __restrict__ w1p,
               float* __restrict__ pooled, float* __restrict__ expout,
               float* __restrict__ segsum, int N, int ntiles)
{
  __shared__ __align__(16) char buf[2][64 * 1024];  // [parity][row][swz 16B chunks]
  __shared__ float sp[2][64];   // [colhalf][node_local] partial scores
  __shared__ float sw[64];      // exp(score) per local row

  const int tid = threadIdx.x;
  const int w = tid >> 6, l = tid & 63;
  const int colhalf = w & 1, wp = w >> 1;
  const int l15 = l & 15, lg = l >> 4;
  const int bid = blockIdx.x;

  if (bid >= ntiles) return;    // never taken at N=5e5; DMA-into-freed-LDS guard

  // ---- preload this wave's 32 W1 B-fragments into registers (128 VGPR) ----
  s16x8 bf[4][8];
  #pragma unroll
  for (int ctl = 0; ctl < 4; ++ctl)
    #pragma unroll
    for (int kt = 0; kt < 8; ++kt)
      bf[ctl][kt] = w1p[(kt * 8 + colhalf * 4 + ctl) * 64 + l];

  float b1v[4], w2v[4];
  #pragma unroll
  for (int ct = 0; ct < 4; ++ct) {
    int c = colhalf * 64 + ct * 16 + l15;
    b1v[ct] = b1[c];
    w2v[ct] = W2[c];
  }
  const float b2s = b2p[0];

  // ---- prologue: stage tile bid into buf[0] (16 row-DMAs per wave) ----
  {
    const int node0 = bid * 64;
    #pragma unroll
    for (int i2 = 0; i2 < 16; ++i2) {
      const int r = i2 * 4 + w;               // wave-uniform local row
      int grow = node0 + r;
      if (grow >= N) grow = N - 1;            // pad rows: discarded later
      dma16(x + (size_t)grow * 256 + ((l ^ (r & 7)) << 2), buf[0] + r * 1024);
    }
  }

  int i = 0;
  for (int ti = bid; ti < ntiles; ti += NPERS, ++i) {
    const int cur = i & 1;
    const int node0 = ti * 64;
    const int tin = ti + NPERS;

    // ---- prefetch next tile, then counted wait: current tile ready ----
    if (tin < ntiles) {
      const int nn0 = tin * 64;
      char* dst = buf[cur ^ 1];
      #pragma unroll
      for (int i2 = 0; i2 < 16; ++i2) {
        const int r = i2 * 4 + w;
        int grow = nn0 + r;
        if (grow >= N) grow = N - 1;
        dma16(x + (size_t)grow * 256 + ((l ^ (r & 7)) << 2), dst + r * 1024);
      }
      asm volatile("s_waitcnt vmcnt(16)" ::: "memory");
    } else {
      asm volatile("s_waitcnt vmcnt(0)" ::: "memory");
    }
    __builtin_amdgcn_s_barrier();
    __builtin_amdgcn_sched_barrier(0);

    const char* tile = buf[cur];

    // ---- Phase A: MFMA scores; wave-pair wp owns rows wp*32..+31 as two
    //      concurrent 16-row tiles, A-fragments from LDS, B from registers ----
    {
      const int r0 = wp * 32 + l15;
      const int r1 = r0 + 16;
      const char* p0 = tile + r0 * 1024;
      const char* p1 = tile + r1 * 1024;
      const int s0 = (r0 & 7), s1 = (r1 & 7);

      f32x4 accA0 = {0.f,0.f,0.f,0.f}, accA1 = {0.f,0.f,0.f,0.f};
      f32x4 accA2 = {0.f,0.f,0.f,0.f}, accA3 = {0.f,0.f,0.f,0.f};
      f32x4 accB0 = {0.f,0.f,0.f,0.f}, accB1 = {0.f,0.f,0.f,0.f};
      f32x4 accB2 = {0.f,0.f,0.f,0.f}, accB3 = {0.f,0.f,0.f,0.f};
      #pragma unroll
      for (int kt = 0; kt < 8; ++kt) {
        const int cc = kt * 8 + lg * 2;       // 16B-chunk index of 8-float slab
        float4 xa0 = *(const float4*)(p0 + (((cc    ) ^ s0) << 4));
        float4 xb0 = *(const float4*)(p0 + (((cc + 1) ^ s0) << 4));
        float4 xa1 = *(const float4*)(p1 + (((cc    ) ^ s1) << 4));
        float4 xb1 = *(const float4*)(p1 + (((cc + 1) ^ s1) << 4));
        s16x8 a0, a1;
        a0[0] = f2bf(xa0.x); a0[1] = f2bf(xa0.y); a0[2] = f2bf(xa0.z); a0[3] = f2bf(xa0.w);
        a0[4] = f2bf(xb0.x); a0[5] = f2bf(xb0.y); a0[6] = f2bf(xb0.z); a0[7] = f2bf(xb0.w);
        a1[0] = f2bf(xa1.x); a1[1] = f2bf(xa1.y); a1[2] = f2bf(xa1.z); a1[3] = f2bf(xa1.w);
        a1[4] = f2bf(xb1.x); a1[5] = f2bf(xb1.y); a1[6] = f2bf(xb1.z); a1[7] = f2bf(xb1.w);
        accA0 = __builtin_amdgcn_mfma_f32_16x16x32_bf16(a0, bf[0][kt], accA0, 0, 0, 0);
        accA1 = __builtin_amdgcn_mfma_f32_16x16x32_bf16(a0, bf[1][kt], accA1, 0, 0, 0);
        accA2 = __builtin_amdgcn_mfma_f32_16x16x32_bf16(a0, bf[2][kt], accA2, 0, 0, 0);
        accA3 = __builtin_amdgcn_mfma_f32_16x16x32_bf16(a0, bf[3][kt], accA3, 0, 0, 0);
        accB0 = __builtin_amdgcn_mfma_f32_16x16x32_bf16(a1, bf[0][kt], accB0, 0, 0, 0);
        accB1 = __builtin_amdgcn_mfma_f32_16x16x32_bf16(a1, bf[1][kt], accB1, 0, 0, 0);
        accB2 = __builtin_amdgcn_mfma_f32_16x16x32_bf16(a1, bf[2][kt], accB2, 0, 0, 0);
        accB3 = __builtin_amdgcn_mfma_f32_16x16x32_bf16(a1, bf[3][kt], accB3, 0, 0, 0);
      }
      // h = tanh(acc + b1); partial score over this wave's 64 cols.
      // D layout: node-in-tile = 4*lg + r, hidden-col = ct*16 + l15.
      float partA[4], partB[4];
      #pragma unroll
      for (int r = 0; r < 4; ++r) {
        float init = colhalf ? 0.f : b2s;
        partA[r] = init
          + fast_tanh(accA0[r] + b1v[0]) * w2v[0]
          + fast_tanh(accA1[r] + b1v[1]) * w2v[1]
          + fast_tanh(accA2[r] + b1v[2]) * w2v[2]
          + fast_tanh(accA3[r] + b1v[3]) * w2v[3];
        partB[r] = init
          + fast_tanh(accB0[r] + b1v[0]) * w2v[0]
          + fast_tanh(accB1[r] + b1v[1]) * w2v[1]
          + fast_tanh(accB2[r] + b1v[2]) * w2v[2]
          + fast_tanh(accB3[r] + b1v[3]) * w2v[3];
      }
      #pragma unroll
      for (int m = 1; m <= 8; m <<= 1) {
        #pragma unroll
        for (int r = 0; r < 4; ++r) {
          partA[r] += __shfl_xor(partA[r], m, 64);
          partB[r] += __shfl_xor(partB[r], m, 64);
        }
      }
      if (l15 == 0) {
        #pragma unroll
        for (int r = 0; r < 4; ++r) {
          sp[colhalf][wp * 32      + lg * 4 + r] = partA[r];
          sp[colhalf][wp * 32 + 16 + lg * 4 + r] = partB[r];
        }
      }
    }
    asm volatile("s_waitcnt lgkmcnt(0)" ::: "memory");
    __builtin_amdgcn_s_barrier();
    __builtin_amdgcn_sched_barrier(0);

    // combine halves, exponentiate (no max needed: |score| <= ~9), store
    if (tid < 64) {
      int node = node0 + tid;
      float e = 0.f;
      if (node < N) {
        e = __expf(sp[0][tid] + sp[1][tid]);
        expout[node] = e;               // unnormalized weight, fixed in finalize
      }
      sw[tid] = e;
    }
    asm volatile("s_waitcnt lgkmcnt(0)" ::: "memory");
    __builtin_amdgcn_s_barrier();
    __builtin_amdgcn_sched_barrier(0);

    // ---- Phase B: pooling from LDS, col = tid ----
    {
      const int nmax = min(64, N - node0);
      int g;
      {
        int lo = 0, hi = NGRAPH - 1;
        while (lo < hi) {
          int mid = (lo + hi) >> 1;
          if (offs[mid + 1] <= node0) lo = mid + 1; else hi = mid;
        }
        g = lo;
      }
      const int ccb = tid >> 2, cib = (tid & 3) << 2;
      int r = 0;
      int nb = offs[g + 1];
      while (r < nmax) {
        const int rend = min(nb - node0, nmax);
        float pacc = 0.f, wsum = 0.f;
        for (; r + 8 <= rend; r += 8) {
          float xv[8], wv[8];
          #pragma unroll
          for (int u = 0; u < 8; ++u) {
            const int rr = r + u;
            xv[u] = *(const float*)(tile + rr * 1024 + (((ccb ^ (rr & 7)) << 4) | cib));
            wv[u] = sw[rr];
          }
          #pragma unroll
          for (int u = 0; u < 8; ++u) {
            pacc += wv[u] * xv[u];
            wsum += wv[u];
          }
        }
        for (; r < rend; ++r) {
          float wv = sw[r];
          pacc += wv * *(const float*)(tile + r * 1024 + (((ccb ^ (r & 7)) << 4) | cib));
          wsum += wv;
        }
        if (wsum > 0.f) {
          atomicAdd(&pooled[(size_t)g * 256 + tid], pacc);
          if (tid == 0) atomicAdd(&segsum[g], wsum);
        }
        if (rend >= nmax) break;
        ++g;
        nb = offs[g + 1];
      }
    }
    __builtin_amdgcn_s_barrier();     // release buf[cur] for next prefetch
    __builtin_amdgcn_sched_barrier(0);
  }
}

// Finalize: pooled /= segsum (0 for empty graphs), weights = exp/segsum[batch].
__global__ void finalize(float* __restrict__ pooled, float* __restrict__ wts,
                         const float* __restrict__ segsum,
                         const void* __restrict__ batch, int N)
{
  int f = blockIdx.x * 256 + threadIdx.x;
  if (f < NGRAPH * 256) {
    int g = f >> 8;
    float s = segsum[g];
    pooled[f] = (s > 0.f) ? pooled[f] / s : 0.f;
  } else {
    int n = f - NGRAPH * 256;
    if (n < N) {
      const int is64 = batch_is64(batch, N);
      int g = (int)getb(batch, n, is64);
      wts[n] = wts[n] / segsum[g];
    }
  }
}

extern "C" void kernel_launch(void* const* d_in, const int* in_sizes, int n_in,
                              void* d_out, int out_size, void* d_ws, size_t ws_size,
                              hipStream_t stream) {
  const float* x     = (const float*)d_in[0];
  const void*  batch = d_in[1];
  const float* W1    = (const float*)d_in[2];
  const float* b1    = (const float*)d_in[3];
  const float* W2    = (const float*)d_in[4];
  const float* b2    = (const float*)d_in[5];
  const int N = in_sizes[0] / 256;
  const int ntiles = (N + 63) / 64;

  float* pooled = (float*)d_out;                          // 4096*256
  float* wout   = (float*)d_out + (size_t)NGRAPH * 256;   // N: exp(s), then weights
  s16x8* w1p    = (s16x8*)d_ws;                           // 64 KB
  int*   offs   = (int*)((char*)d_ws + 64 * 1024);        // 4097 * 4 B
  float* segsum = (float*)((char*)d_ws + 96 * 1024);      // 4096 * 4 B

  // Atomic accumulators must start at zero EVERY call (graph replays included).
  hipMemsetAsync(pooled, 0, (size_t)NGRAPH * 256 * sizeof(float), stream);
  hipMemsetAsync(segsum, 0, (size_t)NGRAPH * sizeof(float), stream);

  prepack_w1<<<16, 256, 0, stream>>>(W1, w1p);
  seg_offsets<<<17, 256, 0, stream>>>(batch, offs, N);
  gate_pool<<<NPERS, 256, 0, stream>>>(x, offs, b1, W2, b2, w1p,
                                       pooled, wout, segsum, N, ntiles);
  const int tot = NGRAPH * 256 + N;
  finalize<<<(tot + 255) / 256, 256, 0, stream>>>(pooled, wout, segsum, batch, N);
}

// Round 10
// 194.279 us; speedup vs baseline: 1.3843x; 1.3843x over previous
//
#include <hip/hip_runtime.h>
#include <hip/hip_bf16.h>

#define NGRAPH 4096

typedef __attribute__((ext_vector_type(8))) short s16x8;
typedef __attribute__((ext_vector_type(4))) float f32x4;
typedef unsigned int u32;

__device__ inline short f2bf(float f) {
  unsigned u = __float_as_uint(f);
  unsigned r = u + 0x7fffu + ((u >> 16) & 1u);
  return (short)(r >> 16);
}

// Prepack W1 (256x128 fp32, row-major) into bf16 MFMA B-fragment order.
// Fragment f = kt*8 + ct (kt,ct in 0..7). Lane l supplies B[k][c] for
// k = kt*32 + (l>>4)*8 + e (e=0..7), c = ct*16 + (l&15).
__global__ void prepack_w1(const float* __restrict__ W1, s16x8* __restrict__ w1p) {
  int t = blockIdx.x * 256 + threadIdx.x;   // 4096 threads total
  int f = t >> 6, l = t & 63;
  int kt = f >> 3, ct = f & 7;
  int k0 = kt * 32 + ((l >> 4) * 8);
  int c  = ct * 16 + (l & 15);
  s16x8 v;
  #pragma unroll
  for (int e = 0; e < 8; ++e) v[e] = f2bf(W1[(k0 + e) * 128 + c]);
  w1p[f * 64 + l] = v;
}

__device__ inline long long getb(const void* b, int i, int is64) {
  if (is64) return ((const long long*)b)[i];
  return (long long)((const int*)b)[i];
}

__device__ inline int lowb(const void* b, int n, long long v, int is64) {
  int lo = 0, hi = n;
  while (lo < hi) {
    int mid = (lo + hi) >> 1;
    if (getb(b, mid, is64) < v) lo = mid + 1; else hi = mid;
  }
  return lo;
}

__device__ inline int batch_is64(const void* batch, int N) {
  // int64 vs int32 materialization probe: an odd 32-bit word index has a zero
  // high word under int64 (values < 2^31), a near-max sorted id under int32.
  int probe = ((N & 1) == 0) ? (N - 1) : (N - 2);
  return (((const int*)batch)[probe] == 0) ? 1 : 0;
}

// One-time: offs[g] = lower_bound(batch, g).
__global__ void seg_offsets(const void* __restrict__ batch, int* __restrict__ offs, int N) {
  int g = blockIdx.x * 256 + threadIdx.x;
  const int is64 = batch_is64(batch, N);
  if (g <= NGRAPH) offs[g] = lowb(batch, N, (long long)g, is64);
}

__device__ inline float fast_tanh(float v) {
  v = fminf(fmaxf(v, -15.f), 15.f);
  float e = __expf(2.f * v);
  return __fdividef(e - 1.f, e + 1.f);
}

__device__ inline void dma16(const float* src, char* ldsdst) {
  __builtin_amdgcn_global_load_lds(
      (const __attribute__((address_space(1))) u32*)src,
      (__attribute__((address_space(3))) u32*)ldsdst,
      16, 0, 0);   // 16 B/lane: lane l -> ldsdst + l*16
}

// Fused kernel (R8 structure + register-resident W1 fragments).
// Block = 64 nodes, 256 threads. x-tile (64 rows x 1 KB) DMA'd once into LDS
// via global_load_lds (async; per-lane source chunk pre-swizzled cc^(row&7));
// W1 B-fragments preloaded to 128 VGPRs (issued AFTER the DMAs so the L2
// reads overlap the HBM stream) -> phase A does ZERO global/L2 loads per kt,
// eliminating the ~128 KB/tile of redundant w1p L2 traffic that contended
// with the DMA stream in R8.
//  Phase A: MFMA gate scores from LDS (dual 16-row tiles per wave-pair).
//  Phase B: pooling from LDS.
// Scores bounded (|s| <= ||W2||_1 + |b2| ~ 9) -> exp without max-subtraction.
// Cross-block segment joins via atomicAdd (buffers zeroed every call).
__global__ __launch_bounds__(256, 2)
void gate_pool(const float* __restrict__ x, const int* __restrict__ offs,
               const float* __restrict__ b1, const float* __restrict__ W2,
               const float* __restrict__ b2p, const s16x8* __restrict__ w1p,
               float* __restrict__ pooled, float* __restrict__ expout,
               float* __restrict__ segsum, int N)
{
  __shared__ __align__(16) char tile[64 * 1024];  // [row][swizzled 16B chunks]
  __shared__ float sp[2][64];   // [colhalf][node_local] partial scores
  __shared__ float sw[64];      // exp(score) per local row

  const int tid = threadIdx.x;
  const int w = tid >> 6, l = tid & 63;
  const int colhalf = w & 1, wp = w >> 1;
  const int l15 = l & 15, lg = l >> 4;
  const int node0 = blockIdx.x * 64;

  // ---- async DMA first: wave w stages rows w, w+4, ..., w+60 (1 KB each) ----
  #pragma unroll
  for (int i = 0; i < 16; ++i) {
    const int r = i * 4 + w;                 // local row (wave-uniform)
    int grow = node0 + r;
    if (grow >= N) grow = N - 1;             // pad rows: discarded later
    // lane l fills LDS chunk l of row r; source chunk = l ^ (r&7) (swizzle)
    const float* src = x + (size_t)grow * 256 + ((l ^ (r & 7)) << 2);
    dma16(src, tile + r * 1024);
  }

  // ---- preload this wave's 32 W1 B-fragments into registers (128 VGPR);
  //      these L2 reads overlap the in-flight HBM DMAs ----
  s16x8 bf[4][8];
  #pragma unroll
  for (int ctl = 0; ctl < 4; ++ctl)
    #pragma unroll
    for (int kt = 0; kt < 8; ++kt)
      bf[ctl][kt] = w1p[(kt * 8 + colhalf * 4 + ctl) * 64 + l];

  float b1v[4], w2v[4];
  #pragma unroll
  for (int ct = 0; ct < 4; ++ct) {
    int c = colhalf * 64 + ct * 16 + l15;
    b1v[ct] = b1[c];
    w2v[ct] = W2[c];
  }
  const float b2s = b2p[0];

  __syncthreads();   // compiler drains vmcnt(0) before barrier -> tile ready

  // ---- Phase A: MFMA gate scores; wave-pair wp owns local rows wp*32..+31
  //      as two concurrent 16-node tiles (A and B), A-frags from LDS, B from
  //      registers. ----
  {
    const int r0 = wp * 32 + l15;            // tile A row
    const int r1 = r0 + 16;                  // tile B row
    const char* p0 = tile + r0 * 1024;
    const char* p1 = tile + r1 * 1024;
    const int s0 = (r0 & 7), s1 = (r1 & 7);

    f32x4 accA0 = {0.f,0.f,0.f,0.f}, accA1 = {0.f,0.f,0.f,0.f};
    f32x4 accA2 = {0.f,0.f,0.f,0.f}, accA3 = {0.f,0.f,0.f,0.f};
    f32x4 accB0 = {0.f,0.f,0.f,0.f}, accB1 = {0.f,0.f,0.f,0.f};
    f32x4 accB2 = {0.f,0.f,0.f,0.f}, accB3 = {0.f,0.f,0.f,0.f};
    #pragma unroll
    for (int kt = 0; kt < 8; ++kt) {
      const int cc = kt * 8 + lg * 2;        // 16B-chunk index of 8-float slab
      float4 xa0 = *(const float4*)(p0 + (((cc    ) ^ s0) << 4));
      float4 xb0 = *(const float4*)(p0 + (((cc + 1) ^ s0) << 4));
      float4 xa1 = *(const float4*)(p1 + (((cc    ) ^ s1) << 4));
      float4 xb1 = *(const float4*)(p1 + (((cc + 1) ^ s1) << 4));
      s16x8 a0, a1;
      a0[0] = f2bf(xa0.x); a0[1] = f2bf(xa0.y); a0[2] = f2bf(xa0.z); a0[3] = f2bf(xa0.w);
      a0[4] = f2bf(xb0.x); a0[5] = f2bf(xb0.y); a0[6] = f2bf(xb0.z); a0[7] = f2bf(xb0.w);
      a1[0] = f2bf(xa1.x); a1[1] = f2bf(xa1.y); a1[2] = f2bf(xa1.z); a1[3] = f2bf(xa1.w);
      a1[4] = f2bf(xb1.x); a1[5] = f2bf(xb1.y); a1[6] = f2bf(xb1.z); a1[7] = f2bf(xb1.w);
      accA0 = __builtin_amdgcn_mfma_f32_16x16x32_bf16(a0, bf[0][kt], accA0, 0, 0, 0);
      accA1 = __builtin_amdgcn_mfma_f32_16x16x32_bf16(a0, bf[1][kt], accA1, 0, 0, 0);
      accA2 = __builtin_amdgcn_mfma_f32_16x16x32_bf16(a0, bf[2][kt], accA2, 0, 0, 0);
      accA3 = __builtin_amdgcn_mfma_f32_16x16x32_bf16(a0, bf[3][kt], accA3, 0, 0, 0);
      accB0 = __builtin_amdgcn_mfma_f32_16x16x32_bf16(a1, bf[0][kt], accB0, 0, 0, 0);
      accB1 = __builtin_amdgcn_mfma_f32_16x16x32_bf16(a1, bf[1][kt], accB1, 0, 0, 0);
      accB2 = __builtin_amdgcn_mfma_f32_16x16x32_bf16(a1, bf[2][kt], accB2, 0, 0, 0);
      accB3 = __builtin_amdgcn_mfma_f32_16x16x32_bf16(a1, bf[3][kt], accB3, 0, 0, 0);
    }
    // h = tanh(acc + b1); partial score = sum h*W2 over this wave's 64 cols.
    // D layout: node-in-tile = 4*lg + r, hidden-col = ct*16 + l15.
    float partA[4], partB[4];
    #pragma unroll
    for (int r = 0; r < 4; ++r) {
      float init = colhalf ? 0.f : b2s;
      partA[r] = init
        + fast_tanh(accA0[r] + b1v[0]) * w2v[0]
        + fast_tanh(accA1[r] + b1v[1]) * w2v[1]
        + fast_tanh(accA2[r] + b1v[2]) * w2v[2]
        + fast_tanh(accA3[r] + b1v[3]) * w2v[3];
      partB[r] = init
        + fast_tanh(accB0[r] + b1v[0]) * w2v[0]
        + fast_tanh(accB1[r] + b1v[1]) * w2v[1]
        + fast_tanh(accB2[r] + b1v[2]) * w2v[2]
        + fast_tanh(accB3[r] + b1v[3]) * w2v[3];
    }
    #pragma unroll
    for (int m = 1; m <= 8; m <<= 1) {
      #pragma unroll
      for (int r = 0; r < 4; ++r) {
        partA[r] += __shfl_xor(partA[r], m, 64);
        partB[r] += __shfl_xor(partB[r], m, 64);
      }
    }
    if (l15 == 0) {
      #pragma unroll
      for (int r = 0; r < 4; ++r) {
        sp[colhalf][wp * 32      + lg * 4 + r] = partA[r];
        sp[colhalf][wp * 32 + 16 + lg * 4 + r] = partB[r];
      }
    }
  }
  __syncthreads();

  // combine halves, exponentiate (no max needed: |score| <= ~9), store
  if (tid < 64) {
    int node = node0 + tid;
    float e = 0.f;
    if (node < N) {
      e = __expf(sp[0][tid] + sp[1][tid]);
      expout[node] = e;                 // unnormalized weight, fixed in finalize
    }
    sw[tid] = e;
  }
  __syncthreads();

  // ---- Phase B: pooling from LDS, col = tid ----
  const int nmax = min(64, N - node0);
  // g: graph containing node0 (upper_bound on offs)
  int g;
  {
    int lo = 0, hi = NGRAPH - 1;
    while (lo < hi) {
      int mid = (lo + hi) >> 1;
      if (offs[mid + 1] <= node0) lo = mid + 1; else hi = mid;
    }
    g = lo;
  }
  const int ccb = tid >> 2, cib = (tid & 3) << 2;   // chunk + in-chunk byte
  int r = 0;
  int nb = offs[g + 1];
  while (r < nmax) {
    const int rend = min(nb - node0, nmax);
    float pacc = 0.f, wsum = 0.f;
    for (; r + 8 <= rend; r += 8) {
      float xv[8], wv[8];
      #pragma unroll
      for (int u = 0; u < 8; ++u) {
        const int rr = r + u;
        xv[u] = *(const float*)(tile + rr * 1024 + (((ccb ^ (rr & 7)) << 4) | cib));
        wv[u] = sw[rr];
      }
      #pragma unroll
      for (int u = 0; u < 8; ++u) {
        pacc += wv[u] * xv[u];
        wsum += wv[u];
      }
    }
    for (; r < rend; ++r) {
      float wv = sw[r];
      pacc += wv * *(const float*)(tile + r * 1024 + (((ccb ^ (r & 7)) << 4) | cib));
      wsum += wv;
    }
    if (wsum > 0.f) {
      atomicAdd(&pooled[(size_t)g * 256 + tid], pacc);
      if (tid == 0) atomicAdd(&segsum[g], wsum);
    }
    if (rend >= nmax) break;
    ++g;
    nb = offs[g + 1];
  }
}

// Finalize: pooled /= segsum (0 for empty graphs), weights = exp/segsum[batch].
__global__ void finalize(float* __restrict__ pooled, float* __restrict__ wts,
                         const float* __restrict__ segsum,
                         const void* __restrict__ batch, int N)
{
  int f = blockIdx.x * 256 + threadIdx.x;
  if (f < NGRAPH * 256) {
    int g = f >> 8;
    float s = segsum[g];
    pooled[f] = (s > 0.f) ? pooled[f] / s : 0.f;
  } else {
    int n = f - NGRAPH * 256;
    if (n < N) {
      const int is64 = batch_is64(batch, N);
      int g = (int)getb(batch, n, is64);
      wts[n] = wts[n] / segsum[g];
    }
  }
}

extern "C" void kernel_launch(void* const* d_in, const int* in_sizes, int n_in,
                              void* d_out, int out_size, void* d_ws, size_t ws_size,
                              hipStream_t stream) {
  const float* x     = (const float*)d_in[0];
  const void*  batch = d_in[1];
  const float* W1    = (const float*)d_in[2];
  const float* b1    = (const float*)d_in[3];
  const float* W2    = (const float*)d_in[4];
  const float* b2    = (const float*)d_in[5];
  const int N = in_sizes[0] / 256;

  float* pooled = (float*)d_out;                          // 4096*256
  float* wout   = (float*)d_out + (size_t)NGRAPH * 256;   // N: exp(s), then weights
  s16x8* w1p    = (s16x8*)d_ws;                           // 64 KB
  int*   offs   = (int*)((char*)d_ws + 64 * 1024);        // 4097 * 4 B
  float* segsum = (float*)((char*)d_ws + 96 * 1024);      // 4096 * 4 B

  // Atomic accumulators must start at zero EVERY call (graph replays included).
  hipMemsetAsync(pooled, 0, (size_t)NGRAPH * 256 * sizeof(float), stream);
  hipMemsetAsync(segsum, 0, (size_t)NGRAPH * sizeof(float), stream);

  prepack_w1<<<16, 256, 0, stream>>>(W1, w1p);
  seg_offsets<<<17, 256, 0, stream>>>(batch, offs, N);
  gate_pool<<<(N + 63) / 64, 256, 0, stream>>>(x, offs, b1, W2, b2, w1p,
                                               pooled, wout, segsum, N);
  const int tot = NGRAPH * 256 + N;
  finalize<<<(tot + 255) / 256, 256, 0, stream>>>(pooled, wout, segsum, batch, N);
}

// Round 11
// 185.724 us; speedup vs baseline: 1.4480x; 1.0461x over previous
//
#include <hip/hip_runtime.h>
#include <hip/hip_bf16.h>

#define NGRAPH 4096

typedef __attribute__((ext_vector_type(8))) short s16x8;
typedef __attribute__((ext_vector_type(4))) float f32x4;
typedef unsigned int u32;

__device__ inline short f2bf(float f) {
  unsigned u = __float_as_uint(f);
  unsigned r = u + 0x7fffu + ((u >> 16) & 1u);
  return (short)(r >> 16);
}

// Prepack W1 (256x128 fp32, row-major) into bf16 MFMA B-fragment order.
// Fragment f = kt*8 + ct (kt,ct in 0..7). Lane l supplies B[k][c] for
// k = kt*32 + (l>>4)*8 + e (e=0..7), c = ct*16 + (l&15).
__global__ void prepack_w1(const float* __restrict__ W1, s16x8* __restrict__ w1p) {
  int t = blockIdx.x * 256 + threadIdx.x;   // 4096 threads total
  int f = t >> 6, l = t & 63;
  int kt = f >> 3, ct = f & 7;
  int k0 = kt * 32 + ((l >> 4) * 8);
  int c  = ct * 16 + (l & 15);
  s16x8 v;
  #pragma unroll
  for (int e = 0; e < 8; ++e) v[e] = f2bf(W1[(k0 + e) * 128 + c]);
  w1p[f * 64 + l] = v;
}

__device__ inline long long getb(const void* b, int i, int is64) {
  if (is64) return ((const long long*)b)[i];
  return (long long)((const int*)b)[i];
}

__device__ inline int lowb(const void* b, int n, long long v, int is64) {
  int lo = 0, hi = n;
  while (lo < hi) {
    int mid = (lo + hi) >> 1;
    if (getb(b, mid, is64) < v) lo = mid + 1; else hi = mid;
  }
  return lo;
}

__device__ inline int batch_is64(const void* batch, int N) {
  // int64 vs int32 materialization probe: an odd 32-bit word index has a zero
  // high word under int64 (values < 2^31), a near-max sorted id under int32.
  int probe = ((N & 1) == 0) ? (N - 1) : (N - 2);
  return (((const int*)batch)[probe] == 0) ? 1 : 0;
}

// One-time: offs[g] = lower_bound(batch, g).
__global__ void seg_offsets(const void* __restrict__ batch, int* __restrict__ offs, int N) {
  int g = blockIdx.x * 256 + threadIdx.x;
  const int is64 = batch_is64(batch, N);
  if (g <= NGRAPH) offs[g] = lowb(batch, N, (long long)g, is64);
}

__device__ inline float fast_tanh(float v) {
  v = fminf(fmaxf(v, -15.f), 15.f);
  float e = __expf(2.f * v);
  return __fdividef(e - 1.f, e + 1.f);
}

__device__ inline void dma16(const float* src, char* ldsdst) {
  __builtin_amdgcn_global_load_lds(
      (const __attribute__((address_space(1))) u32*)src,
      (__attribute__((address_space(3))) u32*)ldsdst,
      16, 0, 0);   // 16 B/lane: lane l -> ldsdst + l*16
}

// Fused kernel, 32-row tiles for 3 blocks/CU (LDS 34 KB/block).
// Rationale: at 2 blocks/CU (R8, 64-row) the blocks phase-lock -> HBM port
// idles during the joint compute window (~45% duty loss). 3 resident blocks
// keep a DMA stream active during any one block's compute.
// Block = 32 nodes, 256 threads. x-tile (32 rows x 1 KB) DMA'd once into LDS
// (async global_load_lds; per-lane source chunk pre-swizzled cc^(row&7)).
//  Phase A: MFMA gate scores from LDS; wave-pair wp owns rows wp*16..+15
//           (single 16-row tile), B-fragments inline from L2-resident w1p.
//  Phase B: pooling from LDS.
// Scores bounded (|s| <= ||W2||_1 + |b2| ~ 9) -> exp without max-subtraction.
// Cross-block segment joins via atomicAdd (buffers zeroed every call).
__global__ __launch_bounds__(256, 3)
void gate_pool(const float* __restrict__ x, const int* __restrict__ offs,
               const float* __restrict__ b1, const float* __restrict__ W2,
               const float* __restrict__ b2p, const s16x8* __restrict__ w1p,
               float* __restrict__ pooled, float* __restrict__ expout,
               float* __restrict__ segsum, int N)
{
  __shared__ __align__(16) char tile[32 * 1024];  // [row][swizzled 16B chunks]
  __shared__ float sp[2][32];   // [colhalf][node_local] partial scores
  __shared__ float sw[32];      // exp(score) per local row

  const int tid = threadIdx.x;
  const int w = tid >> 6, l = tid & 63;
  const int colhalf = w & 1, wp = w >> 1;
  const int l15 = l & 15, lg = l >> 4;
  const int node0 = blockIdx.x * 32;

  // ---- async DMA: wave w stages rows w, w+4, ..., w+28 (1 KB each) ----
  #pragma unroll
  for (int i = 0; i < 8; ++i) {
    const int r = i * 4 + w;                 // local row (wave-uniform)
    int grow = node0 + r;
    if (grow >= N) grow = N - 1;             // pad rows: discarded later
    // lane l fills LDS chunk l of row r; source chunk = l ^ (r&7) (swizzle)
    const float* src = x + (size_t)grow * 256 + ((l ^ (r & 7)) << 2);
    dma16(src, tile + r * 1024);
  }

  float b1v[4], w2v[4];
  #pragma unroll
  for (int ct = 0; ct < 4; ++ct) {
    int c = colhalf * 64 + ct * 16 + l15;
    b1v[ct] = b1[c];
    w2v[ct] = W2[c];
  }
  const float b2s = b2p[0];

  __syncthreads();   // compiler drains vmcnt(0) before barrier -> tile ready

  // ---- Phase A: MFMA gate scores; wave-pair wp owns local rows wp*16..+15,
  //      A-fragments from LDS, B inline from L2-resident w1p ----
  {
    const int r0 = wp * 16 + l15;
    const char* p0 = tile + r0 * 1024;
    const int s0 = (r0 & 7);

    f32x4 acc0 = {0.f,0.f,0.f,0.f}, acc1 = {0.f,0.f,0.f,0.f};
    f32x4 acc2 = {0.f,0.f,0.f,0.f}, acc3 = {0.f,0.f,0.f,0.f};
    #pragma unroll
    for (int kt = 0; kt < 8; ++kt) {
      const int cc = kt * 8 + lg * 2;        // 16B-chunk index of 8-float slab
      float4 xa = *(const float4*)(p0 + (((cc    ) ^ s0) << 4));
      float4 xb = *(const float4*)(p0 + (((cc + 1) ^ s0) << 4));
      const s16x8* wb = w1p + (kt * 8 + colhalf * 4) * 64 + l;   // L2-resident
      s16x8 bf0 = wb[0], bf1 = wb[64], bf2 = wb[128], bf3 = wb[192];
      s16x8 a;
      a[0] = f2bf(xa.x); a[1] = f2bf(xa.y); a[2] = f2bf(xa.z); a[3] = f2bf(xa.w);
      a[4] = f2bf(xb.x); a[5] = f2bf(xb.y); a[6] = f2bf(xb.z); a[7] = f2bf(xb.w);
      acc0 = __builtin_amdgcn_mfma_f32_16x16x32_bf16(a, bf0, acc0, 0, 0, 0);
      acc1 = __builtin_amdgcn_mfma_f32_16x16x32_bf16(a, bf1, acc1, 0, 0, 0);
      acc2 = __builtin_amdgcn_mfma_f32_16x16x32_bf16(a, bf2, acc2, 0, 0, 0);
      acc3 = __builtin_amdgcn_mfma_f32_16x16x32_bf16(a, bf3, acc3, 0, 0, 0);
    }
    // h = tanh(acc + b1); partial score = sum h*W2 over this wave's 64 cols.
    // D layout: node-in-tile = 4*lg + r, hidden-col = ct*16 + l15.
    float part[4];
    #pragma unroll
    for (int r = 0; r < 4; ++r) {
      part[r] = colhalf ? 0.f : b2s;
      part[r] += fast_tanh(acc0[r] + b1v[0]) * w2v[0];
      part[r] += fast_tanh(acc1[r] + b1v[1]) * w2v[1];
      part[r] += fast_tanh(acc2[r] + b1v[2]) * w2v[2];
      part[r] += fast_tanh(acc3[r] + b1v[3]) * w2v[3];
    }
    #pragma unroll
    for (int m = 1; m <= 8; m <<= 1) {
      #pragma unroll
      for (int r = 0; r < 4; ++r) part[r] += __shfl_xor(part[r], m, 64);
    }
    if (l15 == 0) {
      #pragma unroll
      for (int r = 0; r < 4; ++r)
        sp[colhalf][wp * 16 + lg * 4 + r] = part[r];
    }
  }
  __syncthreads();

  // combine halves, exponentiate (no max needed: |score| <= ~9), store
  if (tid < 32) {
    int node = node0 + tid;
    float e = 0.f;
    if (node < N) {
      e = __expf(sp[0][tid] + sp[1][tid]);
      expout[node] = e;                 // unnormalized weight, fixed in finalize
    }
    sw[tid] = e;
  }
  __syncthreads();

  // ---- Phase B: pooling from LDS, col = tid ----
  const int nmax = min(32, N - node0);
  // g: graph containing node0 (upper_bound on offs)
  int g;
  {
    int lo = 0, hi = NGRAPH - 1;
    while (lo < hi) {
      int mid = (lo + hi) >> 1;
      if (offs[mid + 1] <= node0) lo = mid + 1; else hi = mid;
    }
    g = lo;
  }
  const int ccb = tid >> 2, cib = (tid & 3) << 2;   // chunk + in-chunk byte
  int r = 0;
  int nb = offs[g + 1];
  while (r < nmax) {
    const int rend = min(nb - node0, nmax);
    float pacc = 0.f, wsum = 0.f;
    for (; r + 8 <= rend; r += 8) {
      float xv[8], wv[8];
      #pragma unroll
      for (int u = 0; u < 8; ++u) {
        const int rr = r + u;
        xv[u] = *(const float*)(tile + rr * 1024 + (((ccb ^ (rr & 7)) << 4) | cib));
        wv[u] = sw[rr];
      }
      #pragma unroll
      for (int u = 0; u < 8; ++u) {
        pacc += wv[u] * xv[u];
        wsum += wv[u];
      }
    }
    for (; r < rend; ++r) {
      float wv = sw[r];
      pacc += wv * *(const float*)(tile + r * 1024 + (((ccb ^ (r & 7)) << 4) | cib));
      wsum += wv;
    }
    if (wsum > 0.f) {
      atomicAdd(&pooled[(size_t)g * 256 + tid], pacc);
      if (tid == 0) atomicAdd(&segsum[g], wsum);
    }
    if (rend >= nmax) break;
    ++g;
    nb = offs[g + 1];
  }
}

// Finalize: pooled /= segsum (0 for empty graphs), weights = exp/segsum[batch].
__global__ void finalize(float* __restrict__ pooled, float* __restrict__ wts,
                         const float* __restrict__ segsum,
                         const void* __restrict__ batch, int N)
{
  int f = blockIdx.x * 256 + threadIdx.x;
  if (f < NGRAPH * 256) {
    int g = f >> 8;
    float s = segsum[g];
    pooled[f] = (s > 0.f) ? pooled[f] / s : 0.f;
  } else {
    int n = f - NGRAPH * 256;
    if (n < N) {
      const int is64 = batch_is64(batch, N);
      int g = (int)getb(batch, n, is64);
      wts[n] = wts[n] / segsum[g];
    }
  }
}

extern "C" void kernel_launch(void* const* d_in, const int* in_sizes, int n_in,
                              void* d_out, int out_size, void* d_ws, size_t ws_size,
                              hipStream_t stream) {
  const float* x     = (const float*)d_in[0];
  const void*  batch = d_in[1];
  const float* W1    = (const float*)d_in[2];
  const float* b1    = (const float*)d_in[3];
  const float* W2    = (const float*)d_in[4];
  const float* b2    = (const float*)d_in[5];
  const int N = in_sizes[0] / 256;

  float* pooled = (float*)d_out;                          // 4096*256
  float* wout   = (float*)d_out + (size_t)NGRAPH * 256;   // N: exp(s), then weights
  s16x8* w1p    = (s16x8*)d_ws;                           // 64 KB
  int*   offs   = (int*)((char*)d_ws + 64 * 1024);        // 4097 * 4 B
  float* segsum = (float*)((char*)d_ws + 96 * 1024);      // 4096 * 4 B

  // Atomic accumulators must start at zero EVERY call (graph replays included).
  hipMemsetAsync(pooled, 0, (size_t)NGRAPH * 256 * sizeof(float), stream);
  hipMemsetAsync(segsum, 0, (size_t)NGRAPH * sizeof(float), stream);

  prepack_w1<<<16, 256, 0, stream>>>(W1, w1p);
  seg_offsets<<<17, 256, 0, stream>>>(batch, offs, N);
  gate_pool<<<(N + 31) / 32, 256, 0, stream>>>(x, offs, b1, W2, b2, w1p,
                                               pooled, wout, segsum, N);
  const int tot = NGRAPH * 256 + N;
  finalize<<<(tot + 255) / 256, 256, 0, stream>>>(pooled, wout, segsum, batch, N);
}